// Round 13
// baseline (573.075 us; speedup 1.0000x reference)
//
#include <hip/hip_runtime.h>
#include <math.h>

typedef unsigned short u16;
typedef unsigned int u32;
typedef short bf16x8 __attribute__((ext_vector_type(8)));
typedef unsigned short u16x8 __attribute__((ext_vector_type(8)));
typedef float f32x4 __attribute__((ext_vector_type(4)));

#define DEV static __device__ __forceinline__

#define BB 256
#define NN 181
#define DD 512
#define HH 8
#define DKk 64
#define NPAD 192
#define MTOT (BB*NN)          // 46336
#define QKV_ELEMS (23724032u) // B*H*N*64
#define WS_NEEDED 196384768ull
#define BSTR 136              // bounce row stride (u16)

DEV u16 f2bf(float f){
  u32 u = __float_as_uint(f);
  u32 r = (u + 0x7FFFu + ((u >> 16) & 1u)) >> 16;
  return (u16)r;
}
DEV float bf2f(u16 h){ return __uint_as_float(((u32)h) << 16); }
DEV bf16x8 as_bf(u16x8 v){ return __builtin_bit_cast(bf16x8, v); }

DEV void gl_lds16(const u16* g, u16* l){
  __builtin_amdgcn_global_load_lds(
      (const __attribute__((address_space(1))) unsigned int*)g,
      (__attribute__((address_space(3))) unsigned int*)l, 16, 0, 0);
}

// ---------------- unified prep ----------------
DEV void cast8(const float* __restrict__ src, u16* __restrict__ dst, int u){
  const float4* p = reinterpret_cast<const float4*>(src + (size_t)u*8);
  float4 a = p[0], b = p[1];
  u16x8 o;
  o[0]=f2bf(a.x); o[1]=f2bf(a.y); o[2]=f2bf(a.z); o[3]=f2bf(a.w);
  o[4]=f2bf(b.x); o[5]=f2bf(b.y); o[6]=f2bf(b.z); o[7]=f2bf(b.w);
  *reinterpret_cast<u16x8*>(dst + (size_t)u*8) = o;
}

#define SEG_X  2965504
#define SEG_Q  2998272
#define SEG_K  3031040
#define SEG_V  3063808
#define SEG_O  3096576
#define SEG_W1 3227648
#define SEG_W2 3358720
#define SEG_BI 3367936
#define SEG_BC 3368128

__global__ __launch_bounds__(256) void prep_kernel(
    const float* __restrict__ x,  const float* __restrict__ Wq,
    const float* __restrict__ Wk, const float* __restrict__ Wv,
    const float* __restrict__ Wo, const float* __restrict__ w1,
    const float* __restrict__ w2, const float* __restrict__ bq,
    const float* __restrict__ bk, const float* __restrict__ bv,
    const int* __restrict__ mask,
    u16* __restrict__ xb, u16* __restrict__ wqkv, u16* __restrict__ wo_b,
    u16* __restrict__ w1_b, u16* __restrict__ w2_b,
    float* __restrict__ biasA, float* __restrict__ bqkv)
{
  int u = blockIdx.x*256 + threadIdx.x;
  if (u < SEG_X)  { cast8(x,  xb,            u);          return; }
  if (u < SEG_Q)  { cast8(Wq, wqkv,          u - SEG_X);  return; }
  if (u < SEG_K)  { cast8(Wk, wqkv + 262144, u - SEG_Q);  return; }
  if (u < SEG_V)  { cast8(Wv, wqkv + 524288, u - SEG_K);  return; }
  if (u < SEG_O)  { cast8(Wo, wo_b,          u - SEG_V);  return; }
  if (u < SEG_W1) { cast8(w1, w1_b,          u - SEG_O);  return; }
  if (u < SEG_W2) { cast8(w2, w2_b,          u - SEG_W1); return; }
  if (u < SEG_BI) {
    int base = (u - SEG_W2)*8;
    #pragma unroll
    for (int j=0;j<8;++j){
      int idx = base + j;
      int g = idx / (NPAD*NPAD);
      int rem = idx % (NPAD*NPAD);
      int q = rem / NPAD, k = rem % NPAD;
      float v;
      if (k >= NN) v = -INFINITY;
      else if (q >= NN) v = 0.f;
      else {
        bool qv = q < 121, kv = k < 121;
        bool allowed = (g == 0) ? (qv != kv) : (qv == kv);
        if (!allowed) v = -INFINITY;
        else {
          int mb = (g == 0 && !qv) ? mask[k*NN + q] : mask[q*NN + k];
          v = mb ? -1e9f : 0.f;
        }
      }
      biasA[idx] = v;
    }
    return;
  }
  if (u < SEG_BC) {
    int base = (u - SEG_BI)*8;
    #pragma unroll
    for (int j=0;j<8;++j){
      int e = base + j;
      bqkv[e] = (e < 512) ? bq[e] : (e < 1024) ? bk[e-512] : bv[e-1024];
    }
    return;
  }
}

#define SGB __builtin_amdgcn_sched_barrier(0)

// ===== gemmT4: 128x128, BK=32, 4-buffer depth-3 pipeline, 2 blocks/CU =====
// 256 thr = 4 waves (2M x 2N), per-wave 64x64. Addressing algebra identical to
// the r11-verified kernel (same swizzle, same pr/pc). Per K-step: stage kt+3
// (4 gl_lds) -> vmcnt(12) -> barrier(tile kt landed) -> 8 ds_read -> lgkm(0)
// -> barrier(all reads done, frees buf for kt+4) -> 16 MFMA.
// EPI 0: QKV scatter (+0.125 Q); 1: +bias+f32 residual (readback);
// 2: +bias+relu; 5: +bias + bf16 residual (readback).
#define STAGE4(BUF, KT) do{ int kt_=(KT); if(kt_>=ntiles) kt_=0; \
    const u16* a_ = stA + (size_t)kt_*32; \
    const u16* b_ = stB + (size_t)kt_*32; \
    gl_lds16(a_,                  &ldsA[BUF][wave*512]); \
    gl_lds16(a_ + (size_t)64*lda, &ldsA[BUF][2048 + wave*512]); \
    gl_lds16(b_,                  &ldsB[BUF][wave*512]); \
    gl_lds16(b_ + (size_t)64*ldb, &ldsB[BUF][2048 + wave*512]); \
  }while(0)

template<int EPI>
__global__ __launch_bounds__(256, 2) void gemmT4(
    const u16* __restrict__ A, const u16* __restrict__ Bw,
    int K, int N, int lda, int ldb,
    const float* __restrict__ bias,
    u16* __restrict__ outb,
    const float* __restrict__ resf,
    const u16* __restrict__ resb)
{
  __shared__ u16 ldsAll[32768];   // 64 KiB: 4x(A 8KB)+4x(B 8KB) / bounce
  u16 (*ldsA)[4096] = reinterpret_cast<u16(*)[4096]>(ldsAll);
  u16 (*ldsB)[4096] = reinterpret_cast<u16(*)[4096]>(ldsAll + 16384);
  const int tid = threadIdx.x, lane = tid & 63, wave = tid >> 6;
  const int lo = lane & 15, hi = lane >> 4;
  const int wm = wave >> 1, wn = wave & 1;

  // m204 bijective XCD remap, nt-fastest ids
  const int nwg = gridDim.x * gridDim.y;
  const int bid = blockIdx.x + gridDim.x * blockIdx.y;
  const int q8 = nwg >> 3, r8 = nwg & 7;
  const int xcd = bid & 7, j8 = bid >> 3;
  const int wgid = (xcd < r8 ? xcd*(q8+1) : r8*(q8+1) + (xcd-r8)*q8) + j8;
  const int ntb = wgid % gridDim.x, mt = wgid / gridDim.x;
  const int ntiles = K >> 5;

  // staging source (inverse subtile swizzle; dest wave-uniform) — r11-verified
  const int pr = tid >> 2;
  const int pc = ((tid & 3) * 8) ^ (((tid >> 5) & 1) << 4);
  const u16* stA = A  + (size_t)(mt*128  + pr) * lda + pc;
  const u16* stB = Bw + (size_t)(ntb*128 + pr) * ldb + pc;
  // swizzled fragment-read bases — r11-verified
  const int swz = (hi*8) ^ ((lo & 8) << 1);
  const int aRd = wm*2048 + lo*32 + swz;
  const int bRd = wn*2048 + lo*32 + swz;

  f32x4 acc[4][4];
  #pragma unroll
  for (int m=0;m<4;++m)
    #pragma unroll
    for (int n=0;n<4;++n) acc[m][n] = f32x4{0.f,0.f,0.f,0.f};

  // prologue: stage tiles 0,1,2 (12 loads); vmcnt(8) drains tile 0
  STAGE4(0, 0);
  STAGE4(1, 1);
  STAGE4(2, 2);
  asm volatile("s_waitcnt vmcnt(8)" ::: "memory");
  SGB;
  __builtin_amdgcn_s_barrier();
  SGB;

  for (int kt = 0; kt < ntiles; ++kt){
    const int cb = kt & 3;
    STAGE4((kt + 3) & 3, kt + 3);            // stage 3 ahead
    asm volatile("s_waitcnt vmcnt(12)" ::: "memory");  // tile kt landed (mine)
    SGB;
    __builtin_amdgcn_s_barrier();            // beta: tile kt landed for all
    SGB;
    bf16x8 af[4], bg[4];
    #pragma unroll
    for (int m_=0;m_<4;++m_)
      af[m_] = *reinterpret_cast<const bf16x8*>(&ldsA[cb][0] + aRd + m_*512);
    #pragma unroll
    for (int n_=0;n_<4;++n_)
      bg[n_] = *reinterpret_cast<const bf16x8*>(&ldsB[cb][0] + bRd + n_*512);
    asm volatile("s_waitcnt lgkmcnt(0)" ::: "memory");
    SGB;
    __builtin_amdgcn_s_barrier();            // alpha: all reads of buf cb done
    SGB;
    __builtin_amdgcn_s_setprio(1);
    #pragma unroll
    for (int m_=0;m_<4;++m_)
      #pragma unroll
      for (int n_=0;n_<4;++n_)
        acc[m_][n_] = __builtin_amdgcn_mfma_f32_16x16x32_bf16(
            af[m_], bg[n_], acc[m_][n_], 0,0,0);
    __builtin_amdgcn_s_setprio(0);
    SGB;
  }

  // ---------------- LDS-bounce epilogue ----------------
  asm volatile("s_waitcnt vmcnt(0)" ::: "memory");   // drain staging queue
  SGB;
  __builtin_amdgcn_s_barrier();
  SGB;

  float bv[4];
  #pragma unroll
  for (int n=0;n<4;++n) bv[n] = bias[ntb*128 + wn*64 + n*16 + lo];

  #pragma unroll
  for (int m=0;m<4;++m){
    #pragma unroll
    for (int rg=0;rg<4;++rg){
      const int trow = wm*64 + m*16 + hi*4 + rg;
      #pragma unroll
      for (int n=0;n<4;++n){
        const int tcol = wn*64 + n*16 + lo;
        float v = acc[m][n][rg] + bv[n];
        if constexpr (EPI == 0){
          if (((ntb*128 + tcol) >> 9) == 0) v *= 0.125f;   // Q scale
        } else if constexpr (EPI == 2){
          v = fmaxf(v, 0.f);
        }
        ldsAll[trow*BSTR + tcol] = f2bf(v);
      }
    }
  }
  __syncthreads();

  const int rchunk = tid & 15;
  #pragma unroll
  for (int p=0;p<8;++p){
    const int trow = p*16 + (tid >> 4);
    const int grow = mt*128 + trow;
    const int gcol = ntb*128 + rchunk*8;
    u16x8 v = *reinterpret_cast<const u16x8*>(&ldsAll[trow*BSTR + rchunk*8]);
    if constexpr (EPI == 1){
      const float4* rp = reinterpret_cast<const float4*>(resf + (size_t)grow*N + gcol);
      float4 ra = rp[0], rb2 = rp[1];
      float rr[8] = {ra.x,ra.y,ra.z,ra.w,rb2.x,rb2.y,rb2.z,rb2.w};
      #pragma unroll
      for (int i=0;i<8;++i) v[i] = f2bf(bf2f(v[i]) + rr[i]);
    } else if constexpr (EPI == 5){
      u16x8 rv = *reinterpret_cast<const u16x8*>(resb + (size_t)grow*N + gcol);
      #pragma unroll
      for (int i=0;i<8;++i) v[i] = f2bf(bf2f(v[i]) + bf2f(rv[i]));
    }
    if constexpr (EPI == 0){
      const int bi = grow / NN, ni = grow - bi*NN;
      const int which = gcol >> 9, hh = (gcol >> 6) & 7, d = gcol & 63;
      *reinterpret_cast<u16x8*>(outb + (size_t)which*QKV_ELEMS +
          (((size_t)bi*HH + hh)*NN + ni)*DKk + d) = v;
    } else {
      *reinterpret_cast<u16x8*>(outb + (size_t)grow*N + gcol) = v;
    }
  }
}

// ---------------- fused segment attention (r2-r12 verified + T5 setprio) ----------------
__global__ __launch_bounds__(256) void attn_kernel(
    const u16* __restrict__ Qg, const u16* __restrict__ Kg, const u16* __restrict__ Vg,
    const float* __restrict__ biasA, u16* __restrict__ ctx)
{
  __shared__ u16 Kb[NPAD*72];
  __shared__ u16 Vt[64*200];
  __shared__ u16 Pl[4*16*200];
  const int tid = threadIdx.x, lane = tid & 63, wave = tid >> 6;
  const int lo = lane & 15, hi = lane >> 4;
  const int bh = blockIdx.x;
  const int h = bh & 7, g = h >> 2, b = bh >> 3;
  const size_t base = (size_t)bh * NN * DKk;

  #pragma unroll
  for (int it=0; it<6; ++it){
    int row = it*32 + (tid >> 3);
    int cb = (tid & 7)*8;
    u16x8 val = {0,0,0,0,0,0,0,0};
    if (row < NN) val = *reinterpret_cast<const u16x8*>(Kg + base + (size_t)row*DKk + cb);
    *reinterpret_cast<u16x8*>(&Kb[row*72 + cb]) = val;
  }
  #pragma unroll
  for (int it=0; it<6; ++it){
    int row = it*32 + (tid >> 3);
    int cb = (tid & 7)*8;
    u16x8 val = {0,0,0,0,0,0,0,0};
    if (row < NN) val = *reinterpret_cast<const u16x8*>(Vg + base + (size_t)row*DKk + cb);
    *reinterpret_cast<u16x8*>(&Pl[row*64 + cb]) = val;
  }
  __syncthreads();
  #pragma unroll
  for (int j=0;j<6;++j){
    int task = j*256 + tid;
    int d = task & 63;
    int nc = task >> 6;
    u16x8 tv;
    #pragma unroll
    for (int i=0;i<8;++i) tv[i] = Pl[(nc*8+i)*64 + d];
    *reinterpret_cast<u16x8*>(&Vt[d*200 + nc*8]) = tv;
  }
  __syncthreads();

  u16* pw = Pl + wave*16*200;

  for (int rb = wave; rb < 12; rb += 4){
    const int q0 = rb*16;
    const int qrow = q0 + lo;
    bf16x8 qa[2];
    #pragma unroll
    for (int kk=0;kk<2;++kk){
      u16x8 val = {0,0,0,0,0,0,0,0};
      if (qrow < NN) val = *reinterpret_cast<const u16x8*>(Qg + base + (size_t)qrow*DKk + kk*32 + hi*8);
      qa[kk] = as_bf(val);
    }
    f32x4 s[12];
    __builtin_amdgcn_s_setprio(1);
    #pragma unroll
    for (int c=0;c<12;++c){
      f32x4 a = f32x4{0.f,0.f,0.f,0.f};
      #pragma unroll
      for (int kk=0;kk<2;++kk){
        bf16x8 kb = *reinterpret_cast<const bf16x8*>(&Kb[(c*16+lo)*72 + kk*32 + hi*8]);
        a = __builtin_amdgcn_mfma_f32_16x16x32_bf16(qa[kk], kb, a, 0,0,0);
      }
      s[c] = a;
    }
    __builtin_amdgcn_s_setprio(0);
    const float* brow = biasA + ((size_t)g*NPAD + q0 + hi*4)*NPAD + lo;
    #pragma unroll
    for (int r=0;r<4;++r)
      #pragma unroll
      for (int c=0;c<12;++c)
        s[c][r] += brow[r*NPAD + c*16];
    float inv[4];
    #pragma unroll
    for (int r=0;r<4;++r){
      float m = s[0][r];
      #pragma unroll
      for (int c=1;c<12;++c) m = fmaxf(m, s[c][r]);
      #pragma unroll
      for (int off=1; off<16; off<<=1) m = fmaxf(m, __shfl_xor(m, off, 64));
      float t = 0.f;
      #pragma unroll
      for (int c=0;c<12;++c){ float e = __expf(s[c][r] - m); s[c][r] = e; t += e; }
      #pragma unroll
      for (int off=1; off<16; off<<=1) t += __shfl_xor(t, off, 64);
      inv[r] = 1.0f / t;
    }
    #pragma unroll
    for (int c=0;c<12;++c)
      #pragma unroll
      for (int r=0;r<4;++r)
        pw[(hi*4+r)*200 + c*16 + lo] = f2bf(s[c][r] * inv[r]);
    asm volatile("s_waitcnt lgkmcnt(0)" ::: "memory");
    __builtin_amdgcn_sched_barrier(0);
    bf16x8 pa[6];
    #pragma unroll
    for (int c6=0;c6<6;++c6)
      pa[c6] = *reinterpret_cast<const bf16x8*>(&pw[lo*200 + c6*32 + hi*8]);
    __builtin_amdgcn_s_setprio(1);
    #pragma unroll
    for (int dt=0;dt<4;++dt){
      f32x4 a = f32x4{0.f,0.f,0.f,0.f};
      #pragma unroll
      for (int c6=0;c6<6;++c6){
        bf16x8 vb = *reinterpret_cast<const bf16x8*>(&Vt[(dt*16+lo)*200 + c6*32 + hi*8]);
        a = __builtin_amdgcn_mfma_f32_16x16x32_bf16(pa[c6], vb, a, 0,0,0);
      }
      #pragma unroll
      for (int r=0;r<4;++r){
        int q = q0 + hi*4 + r;
        if (q < NN)
          ctx[((size_t)b*NN + q)*DD + h*DKk + dt*16 + lo] = f2bf(a[r]);
      }
    }
    __builtin_amdgcn_s_setprio(0);
  }
}

// ---------------- LayerNorm over D=512, one wave per row ----------------
template<int OUTF32>
__global__ __launch_bounds__(256) void ln_kernel(
    const u16* __restrict__ in, const float* __restrict__ gamma,
    const float* __restrict__ beta, void* __restrict__ outp)
{
  const int row = blockIdx.x*4 + (threadIdx.x >> 6);
  const int lane = threadIdx.x & 63;
  u16x8 rv = *reinterpret_cast<const u16x8*>(in + (size_t)row*512 + lane*8);
  float x[8]; float s = 0.f, s2 = 0.f;
  #pragma unroll
  for (int i=0;i<8;++i){ x[i] = bf2f(rv[i]); s += x[i]; s2 += x[i]*x[i]; }
  #pragma unroll
  for (int off=32; off>=1; off>>=1){ s += __shfl_xor(s, off, 64); s2 += __shfl_xor(s2, off, 64); }
  const float mu = s * (1.f/512.f);
  const float var = s2 * (1.f/512.f) - mu*mu;
  const float rstd = rsqrtf(var + 1e-5f);
  float4 ga = *reinterpret_cast<const float4*>(gamma + lane*8);
  float4 gb = *reinterpret_cast<const float4*>(gamma + lane*8 + 4);
  float4 ba = *reinterpret_cast<const float4*>(beta + lane*8);
  float4 bb = *reinterpret_cast<const float4*>(beta + lane*8 + 4);
  float gg[8] = {ga.x,ga.y,ga.z,ga.w,gb.x,gb.y,gb.z,gb.w};
  float bt[8] = {ba.x,ba.y,ba.z,ba.w,bb.x,bb.y,bb.z,bb.w};
  if constexpr (OUTF32){
    float o[8];
    #pragma unroll
    for (int i=0;i<8;++i) o[i] = (x[i]-mu)*rstd*gg[i] + bt[i];
    float4* op = reinterpret_cast<float4*>((float*)outp + (size_t)row*512 + lane*8);
    op[0] = make_float4(o[0],o[1],o[2],o[3]);
    op[1] = make_float4(o[4],o[5],o[6],o[7]);
  } else {
    u16x8 o;
    #pragma unroll
    for (int i=0;i<8;++i) o[i] = f2bf((x[i]-mu)*rstd*gg[i] + bt[i]);
    *reinterpret_cast<u16x8*>((u16*)outp + (size_t)row*512 + lane*8) = o;
  }
}

// ---------------- launch ----------------
// ws map (total 196,384,768 B) — r2-r12 verified layout:
//   [0        ..  2097152) w1_b     [2097152 ..  4194304) w2_b
//   [4194304  ..  5767168) wqkv     [5767168 ..  6291456) wo_b
//   [6291456  ..  6586368) biasA    [6586368 ..  6592512) bqkv
//   [6592512  .. 54040576) xb : x bf16 -> ctx (x f32 residual read from d_in)
//   [54040576 ..101488640) qbuf: Q -> r1
//   [101488640..148936704) kbuf: K -> h
//   [148936704..196384768) vbuf: V -> s2
//   ffbuf = ws+4194304: FF1 chunk 23296x2048x2B = 95,420,416 ends 99,614,720 < kbuf
extern "C" void kernel_launch(void* const* d_in, const int* in_sizes, int n_in,
                              void* d_out, int out_size, void* d_ws, size_t ws_size,
                              hipStream_t stream)
{
  if (ws_size < WS_NEEDED) return;

  const float* x   = (const float*)d_in[0];
  const int*   mask= (const int*)  d_in[1];
  const float* Wq  = (const float*)d_in[2];
  const float* bq  = (const float*)d_in[3];
  const float* Wk  = (const float*)d_in[4];
  const float* bk  = (const float*)d_in[5];
  const float* Wv  = (const float*)d_in[6];
  const float* bv  = (const float*)d_in[7];
  const float* Wo  = (const float*)d_in[8];
  const float* bo  = (const float*)d_in[9];
  const float* w1  = (const float*)d_in[10];
  const float* b1  = (const float*)d_in[11];
  const float* w2  = (const float*)d_in[12];
  const float* b2  = (const float*)d_in[13];
  const float* g1  = (const float*)d_in[14];
  const float* be1 = (const float*)d_in[15];
  const float* g2  = (const float*)d_in[16];
  const float* be2 = (const float*)d_in[17];

  char* ws = (char*)d_ws;
  u16*   w1_b  = (u16*)  (ws + 0);
  u16*   w2_b  = (u16*)  (ws + 2097152);
  u16*   wqkv  = (u16*)  (ws + 4194304);
  u16*   wo_b  = (u16*)  (ws + 5767168);
  float* biasA = (float*)(ws + 6291456);
  float* bqkv  = (float*)(ws + 6586368);
  u16*   xb    = (u16*)  (ws + 6592512);
  u16*   qbuf  = (u16*)  (ws + 54040576);
  u16*   kbuf  = qbuf + QKV_ELEMS;
  u16*   vbuf  = qbuf + 2*QKV_ELEMS;
  u16*   ffbuf = (u16*)  (ws + 4194304);

  // one fused prep launch
  prep_kernel<<<13157, 256, 0, stream>>>(x, Wq, Wk, Wv, Wo, w1, w2, bq, bk, bv,
                                         mask, xb, wqkv, wo_b, w1_b, w2_b, biasA, bqkv);

  // QKV projection (scatter to [B,H,N,64] bf16, Q scaled by 1/8)
  gemmT4<0><<<dim3(12,362), 256, 0, stream>>>(xb, wqkv, 512, 1536, 512, 512,
                                              bqkv, qbuf, nullptr, nullptr);
  // fused segment attention -> ctx (overwrites xb; x f32 stays in d_in)
  attn_kernel<<<2048, 256, 0, stream>>>(qbuf, kbuf, vbuf, biasA, xb);
  // Wo projection + bo + x (f32) residual -> r1 (qbuf)
  gemmT4<1><<<dim3(4,362), 256, 0, stream>>>(xb, wo_b, 512, 512, 512, 512,
                                             bo, qbuf, x, nullptr);
  // LN1 -> h (kbuf)
  ln_kernel<0><<<11584, 256, 0, stream>>>(qbuf, g1, be1, kbuf);
  // FFN split-M: chunks of 23296 + 23040 rows
  {
    const size_t ro = (size_t)23296 * 512;
    gemmT4<2><<<dim3(16,182), 256, 0, stream>>>(kbuf, w1_b, 512, 2048, 512, 512,
                                                b1, ffbuf, nullptr, nullptr);
    gemmT4<5><<<dim3(4,182), 256, 0, stream>>>(ffbuf, w2_b, 2048, 512, 2048, 2048,
                                               b2, vbuf, nullptr, kbuf);
    gemmT4<2><<<dim3(16,180), 256, 0, stream>>>(kbuf + ro, w1_b, 512, 2048, 512, 512,
                                                b1, ffbuf, nullptr, nullptr);
    gemmT4<5><<<dim3(4,180), 256, 0, stream>>>(ffbuf, w2_b, 2048, 512, 2048, 2048,
                                               b2, vbuf + ro, nullptr, kbuf + ro);
  }
  // LN2 -> d_out (fp32)
  ln_kernel<1><<<11584, 256, 0, stream>>>(vbuf, g2, be2, d_out);
}

// Round 14
// 518.194 us; speedup vs baseline: 1.1059x; 1.1059x over previous
//
#include <hip/hip_runtime.h>
#include <math.h>

typedef unsigned short u16;
typedef unsigned int u32;
typedef short bf16x8 __attribute__((ext_vector_type(8)));
typedef unsigned short u16x8 __attribute__((ext_vector_type(8)));
typedef float f32x4 __attribute__((ext_vector_type(4)));

#define DEV static __device__ __forceinline__

#define BB 256
#define NN 181
#define DD 512
#define HH 8
#define DKk 64
#define NPAD 192
#define MTOT (BB*NN)          // 46336
#define QKV_ELEMS (23724032u) // B*H*N*64
#define WS_NEEDED 196384768ull
#define BSTR 136              // gemmT bounce row stride (u16)
#define ESTR 264              // gemm8 bounce row stride (u16)

DEV u16 f2bf(float f){
  u32 u = __float_as_uint(f);
  u32 r = (u + 0x7FFFu + ((u >> 16) & 1u)) >> 16;
  return (u16)r;
}
DEV float bf2f(u16 h){ return __uint_as_float(((u32)h) << 16); }
DEV bf16x8 as_bf(u16x8 v){ return __builtin_bit_cast(bf16x8, v); }

DEV void gl_lds16(const u16* g, u16* l){
  __builtin_amdgcn_global_load_lds(
      (const __attribute__((address_space(1))) unsigned int*)g,
      (__attribute__((address_space(3))) unsigned int*)l, 16, 0, 0);
}

// ---------------- unified prep ----------------
DEV void cast8(const float* __restrict__ src, u16* __restrict__ dst, int u){
  const float4* p = reinterpret_cast<const float4*>(src + (size_t)u*8);
  float4 a = p[0], b = p[1];
  u16x8 o;
  o[0]=f2bf(a.x); o[1]=f2bf(a.y); o[2]=f2bf(a.z); o[3]=f2bf(a.w);
  o[4]=f2bf(b.x); o[5]=f2bf(b.y); o[6]=f2bf(b.z); o[7]=f2bf(b.w);
  *reinterpret_cast<u16x8*>(dst + (size_t)u*8) = o;
}

#define SEG_X  2965504
#define SEG_Q  2998272
#define SEG_K  3031040
#define SEG_V  3063808
#define SEG_O  3096576
#define SEG_W1 3227648
#define SEG_W2 3358720
#define SEG_BI 3367936
#define SEG_BC 3368128

__global__ __launch_bounds__(256) void prep_kernel(
    const float* __restrict__ x,  const float* __restrict__ Wq,
    const float* __restrict__ Wk, const float* __restrict__ Wv,
    const float* __restrict__ Wo, const float* __restrict__ w1,
    const float* __restrict__ w2, const float* __restrict__ bq,
    const float* __restrict__ bk, const float* __restrict__ bv,
    const int* __restrict__ mask,
    u16* __restrict__ xb, u16* __restrict__ wqkv, u16* __restrict__ wo_b,
    u16* __restrict__ w1_b, u16* __restrict__ w2_b,
    float* __restrict__ biasA, float* __restrict__ bqkv)
{
  int u = blockIdx.x*256 + threadIdx.x;
  if (u < SEG_X)  { cast8(x,  xb,            u);          return; }
  if (u < SEG_Q)  { cast8(Wq, wqkv,          u - SEG_X);  return; }
  if (u < SEG_K)  { cast8(Wk, wqkv + 262144, u - SEG_Q);  return; }
  if (u < SEG_V)  { cast8(Wv, wqkv + 524288, u - SEG_K);  return; }
  if (u < SEG_O)  { cast8(Wo, wo_b,          u - SEG_V);  return; }
  if (u < SEG_W1) { cast8(w1, w1_b,          u - SEG_O);  return; }
  if (u < SEG_W2) { cast8(w2, w2_b,          u - SEG_W1); return; }
  if (u < SEG_BI) {
    int base = (u - SEG_W2)*8;
    #pragma unroll
    for (int j=0;j<8;++j){
      int idx = base + j;
      int g = idx / (NPAD*NPAD);
      int rem = idx % (NPAD*NPAD);
      int q = rem / NPAD, k = rem % NPAD;
      float v;
      if (k >= NN) v = -INFINITY;
      else if (q >= NN) v = 0.f;
      else {
        bool qv = q < 121, kv = k < 121;
        bool allowed = (g == 0) ? (qv != kv) : (qv == kv);
        if (!allowed) v = -INFINITY;
        else {
          int mb = (g == 0 && !qv) ? mask[k*NN + q] : mask[q*NN + k];
          v = mb ? -1e9f : 0.f;
        }
      }
      biasA[idx] = v;
    }
    return;
  }
  if (u < SEG_BC) {
    int base = (u - SEG_BI)*8;
    #pragma unroll
    for (int j=0;j<8;++j){
      int e = base + j;
      bqkv[e] = (e < 512) ? bq[e] : (e < 1024) ? bk[e-512] : bv[e-1024];
    }
    return;
  }
}

#define SGB __builtin_amdgcn_sched_barrier(0)

// ========== gemm8: m201-style 256x256 8-phase zigzag (r12-verified, FF1) ==========
#define RDA8(CB, MH) do{ \
    _Pragma("unroll") for(int m_=0;m_<4;++m_) \
      _Pragma("unroll") for(int k_=0;k_<2;++k_) \
        afx[m_][k_] = *reinterpret_cast<const bf16x8*>( \
            &ldsT[CB][0][MH][0] + aRdBase + m_*2048 + k_*512); \
  }while(0)
#define RDB4(CB, NH, BG) do{ \
    _Pragma("unroll") for(int n_=0;n_<2;++n_) \
      _Pragma("unroll") for(int k_=0;k_<2;++k_) \
        BG[n_][k_] = *reinterpret_cast<const bf16x8*>( \
            &ldsT[CB][1][NH][0] + bRdBase + n_*4096 + k_*512); \
  }while(0)
#define STG(SB, SO, SH, KT) do{ int kt_=(KT); if(kt_>=ntiles) kt_=0; \
    const int ld_ = (SO)==0? lda: ldb; \
    const u16* s_ = ((SO)==0? stA: stB) + (size_t)(SH)*128*ld_ + (size_t)kt_*64; \
    gl_lds16(s_, &ldsT[SB][SO][SH][wave*512]); \
    gl_lds16(s_ + (size_t)64*ld_, &ldsT[SB][SO][SH][wave*512+4096]); \
  }while(0)
#define BARS do{ SGB; __builtin_amdgcn_s_barrier(); SGB; }while(0)
#define MF16(MH, NH, BG) do{ __builtin_amdgcn_s_setprio(1); \
    _Pragma("unroll") for(int m_=0;m_<4;++m_) \
      _Pragma("unroll") for(int n_=0;n_<2;++n_) \
        _Pragma("unroll") for(int k_=0;k_<2;++k_) \
          acc[(MH)*4+m_][(NH)*2+n_] = __builtin_amdgcn_mfma_f32_16x16x32_bf16( \
              afx[m_][k_], BG[n_][k_], acc[(MH)*4+m_][(NH)*2+n_], 0,0,0); \
    __builtin_amdgcn_s_setprio(0); \
  }while(0)
#define VM6 asm volatile("s_waitcnt vmcnt(6)" ::: "memory")

template<int EPI>
__global__ __launch_bounds__(512, 2) void gemm8(
    const u16* __restrict__ A, const u16* __restrict__ Bw,
    int K, int N, int lda, int ldb,
    const float* __restrict__ bias,
    u16* __restrict__ outb)
{
  __shared__ u16 ldsAll8[65536];
  u16 (*ldsT)[2][2][8192] = reinterpret_cast<u16(*)[2][2][8192]>(ldsAll8);
  const int tid = threadIdx.x, lane = tid & 63, wave = tid >> 6;
  const int lo = lane & 15, hi = lane >> 4;
  const int wm = wave >> 2, wn = wave & 3;

  const int nwg = gridDim.x * gridDim.y;
  const int bid = blockIdx.x + gridDim.x * blockIdx.y;
  const int q8 = nwg >> 3, r8 = nwg & 7;
  const int xcd = bid & 7, j8 = bid >> 3;
  const int wgid = (xcd < r8 ? xcd*(q8+1) : r8*(q8+1) + (xcd-r8)*q8) + j8;
  const int ntb = wgid % gridDim.x, mt = wgid / gridDim.x;
  const int ntiles = K >> 6, niter = ntiles >> 1;

  const int pr = ((tid >> 7) << 4) | ((tid >> 2) & 15);
  const int pc = (((tid >> 6) & 1) << 5) | (((tid & 3) * 8) ^ (((tid >> 5) & 1) << 4));
  const u16* stA = A  + (size_t)(mt*256 + pr) * lda + pc;
  const u16* stB = Bw + (size_t)(ntb*256 + pr) * ldb + pc;
  const int swz = (hi*8) ^ ((lo & 8) << 1);
  const int aRdBase = wm*1024 + lo*32 + swz;
  const int bRdBase = wn*1024 + lo*32 + swz;

  f32x4 acc[8][4];
  #pragma unroll
  for (int f=0; f<8; ++f)
    #pragma unroll
    for (int n=0; n<4; ++n) acc[f][n] = f32x4{0.f,0.f,0.f,0.f};

  STG(0,0,0, 0); STG(0,1,0, 0); STG(0,1,1, 0); STG(0,0,1, 0);
  STG(1,0,0, 1); STG(1,1,0, 1); STG(1,1,1, 1);
  VM6;
  BARS;

  for (int i = 0; i < niter; ++i){
    const int v1 = 2*i+1, u2 = 2*i+2, v2 = 2*i+3;
    bf16x8 afx[4][2], bg0[2][2], bg1[2][2];
    RDA8(0,0); RDB4(0,0,bg0); STG(1,0,1, v1);      BARS; MF16(0,0,bg0); BARS;
    RDB4(0,1,bg1);            STG(0,0,0, u2);      BARS; MF16(0,1,bg1); BARS;
    RDA8(0,1);                STG(0,1,0, u2);      BARS; MF16(1,1,bg1); BARS;
    STG(0,1,1, u2); VM6;                           BARS; MF16(1,0,bg0); BARS;
    RDA8(1,0); RDB4(1,0,bg0); STG(0,0,1, u2);      BARS; MF16(0,0,bg0); BARS;
    RDB4(1,1,bg1);            STG(1,0,0, v2);      BARS; MF16(0,1,bg1); BARS;
    RDA8(1,1);                STG(1,1,0, v2);      BARS; MF16(1,1,bg1); BARS;
    STG(1,1,1, v2); VM6;                           BARS; MF16(1,0,bg0); BARS;
  }
  asm volatile("s_waitcnt vmcnt(0)" ::: "memory");
  BARS;

  float bv[4];
  #pragma unroll
  for (int n=0; n<4; ++n) bv[n] = bias[ntb*256 + wn*16 + n*64 + lo];

  #pragma unroll
  for (int q=0; q<2; ++q){
    #pragma unroll
    for (int m_=0; m_<4; ++m_){
      const int f = q*4 + m_;
      #pragma unroll
      for (int rg=0; rg<4; ++rg){
        const int trow = wm*16 + m_*32 + hi*4 + rg;
        #pragma unroll
        for (int n=0; n<4; ++n){
          const int tcol = wn*16 + n*64 + lo;
          float v = acc[f][n][rg] + bv[n];
          if constexpr (EPI == 0){
            if (((ntb*256 + tcol) >> 9) == 0) v *= 0.125f;
          } else {
            v = fmaxf(v, 0.f);
          }
          ldsAll8[trow*ESTR + tcol] = f2bf(v);
        }
      }
    }
    __syncthreads();
    const int rchunk = tid & 31;
    #pragma unroll
    for (int p=0; p<8; ++p){
      const int row = p*16 + (tid >> 5);
      const int grow = mt*256 + q*128 + row;
      const int gcol = ntb*256 + rchunk*8;
      u16x8 v = *reinterpret_cast<const u16x8*>(&ldsAll8[row*ESTR + rchunk*8]);
      if constexpr (EPI == 0){
        const int bi = grow / NN, ni = grow - bi*NN;
        const int which = gcol >> 9, hh = (gcol >> 6) & 7, d = gcol & 63;
        *reinterpret_cast<u16x8*>(outb + (size_t)which*QKV_ELEMS +
            (((size_t)bi*HH + hh)*NN + ni)*DKk + d) = v;
      } else {
        *reinterpret_cast<u16x8*>(outb + (size_t)grow*N + gcol) = v;
      }
    }
    __syncthreads();
  }
}

// ========== gemmT 128x128 4-wave (r10-verified incl. EPI0) for QKV/Wo/FF2 ==========
#define STAGE(BUF, KT) do { int kt_=(KT); if (kt_>=ntiles) kt_=0; \
    const u16* a_ = stA + (size_t)kt_*64; \
    const u16* b_ = stB + (size_t)kt_*64; \
    gl_lds16(a_,                       &ldsA[BUF][0][wave*512]); \
    gl_lds16(a_ + 32,                  &ldsA[BUF][1][wave*512]); \
    gl_lds16(a_ + (size_t)64*lda,      &ldsA[BUF][0][wave*512 + 2048]); \
    gl_lds16(a_ + (size_t)64*lda + 32, &ldsA[BUF][1][wave*512 + 2048]); \
    gl_lds16(b_,                       &ldsB[BUF][0][wave*512]); \
    gl_lds16(b_ + 32,                  &ldsB[BUF][1][wave*512]); \
    gl_lds16(b_ + (size_t)64*ldb,      &ldsB[BUF][0][wave*512 + 2048]); \
    gl_lds16(b_ + (size_t)64*ldb + 32, &ldsB[BUF][1][wave*512 + 2048]); \
  } while(0)

template<int EPI>
__global__ __launch_bounds__(256, 2) void gemmT(
    const u16* __restrict__ A, const u16* __restrict__ Bw,
    int K, int N, int lda, int ldb,
    const float* __restrict__ bias,
    u16* __restrict__ outb,
    const float* __restrict__ resf,
    const u16* __restrict__ resb)
{
  __shared__ u16 ldsAll[32768];
  u16 (*ldsA)[2][4096] = reinterpret_cast<u16(*)[2][4096]>(ldsAll);
  u16 (*ldsB)[2][4096] = reinterpret_cast<u16(*)[2][4096]>(ldsAll + 16384);
  const int tid = threadIdx.x, lane = tid & 63, wave = tid >> 6;
  const int lo = lane & 15, hi = lane >> 4;
  const int wm = wave >> 1, wn = wave & 1;

  const int nwg = gridDim.x * gridDim.y;
  const int bid = blockIdx.x + gridDim.x * blockIdx.y;
  const int q8 = nwg >> 3, r8 = nwg & 7;
  const int xcd = bid & 7, j8 = bid >> 3;
  const int wgid = (xcd < r8 ? xcd*(q8+1) : r8*(q8+1) + (xcd-r8)*q8) + j8;
  const int ntb = wgid % gridDim.x, mt = wgid / gridDim.x;
  const int ntiles = K >> 6;

  const int pr = tid >> 2;
  const int pc = ((tid & 3) * 8) ^ (((tid >> 5) & 1) << 4);
  const u16* stA = A  + (size_t)(mt*128  + pr) * lda + pc;
  const u16* stB = Bw + (size_t)(ntb*128 + pr) * ldb + pc;
  const int swz = (hi*8) ^ ((lo & 8) << 1);
  const int aRd = wm*2048 + lo*32 + swz;
  const int bRd = wn*2048 + lo*32 + swz;

  f32x4 acc[4][4];
  #pragma unroll
  for (int m=0;m<4;++m)
    #pragma unroll
    for (int n=0;n<4;++n) acc[m][n] = f32x4{0.f,0.f,0.f,0.f};

  STAGE(0, 0);
  STAGE(1, 1);
  asm volatile("s_waitcnt vmcnt(8)" ::: "memory");
  SGB;
  __builtin_amdgcn_s_barrier();
  SGB;

  #pragma unroll 2
  for (int kt = 0; kt < ntiles; ++kt){
    const int cb = kt & 1;
    bf16x8 af[4][2], bg[4][2];
    #pragma unroll
    for (int k_=0;k_<2;++k_){
      const u16* ah = &ldsA[cb][k_][0];
      const u16* bh = &ldsB[cb][k_][0];
      #pragma unroll
      for (int m_=0;m_<4;++m_)
        af[m_][k_] = *reinterpret_cast<const bf16x8*>(ah + aRd + m_*512);
      #pragma unroll
      for (int n_=0;n_<4;++n_)
        bg[n_][k_] = *reinterpret_cast<const bf16x8*>(bh + bRd + n_*512);
    }
    asm volatile("s_waitcnt lgkmcnt(0)" ::: "memory");
    SGB;
    __builtin_amdgcn_s_barrier();
    SGB;
    STAGE(cb, kt + 2);
    asm volatile("s_waitcnt vmcnt(8)" ::: "memory");
    SGB;
    __builtin_amdgcn_s_barrier();
    SGB;
    __builtin_amdgcn_s_setprio(1);
    #pragma unroll
    for (int m_=0;m_<4;++m_)
      #pragma unroll
      for (int n_=0;n_<4;++n_)
        #pragma unroll
        for (int k_=0;k_<2;++k_)
          acc[m_][n_] = __builtin_amdgcn_mfma_f32_16x16x32_bf16(
              af[m_][k_], bg[n_][k_], acc[m_][n_], 0,0,0);
    __builtin_amdgcn_s_setprio(0);
    SGB;
  }

  asm volatile("s_waitcnt vmcnt(0)" ::: "memory");
  SGB;
  __builtin_amdgcn_s_barrier();
  SGB;

  float bv[4];
  #pragma unroll
  for (int n=0;n<4;++n) bv[n] = bias[ntb*128 + wn*64 + n*16 + lo];

  #pragma unroll
  for (int m=0;m<4;++m){
    #pragma unroll
    for (int rg=0;rg<4;++rg){
      const int trow = wm*64 + m*16 + hi*4 + rg;
      #pragma unroll
      for (int n=0;n<4;++n){
        const int tcol = wn*64 + n*16 + lo;
        float v = acc[m][n][rg] + bv[n];
        if constexpr (EPI == 0){
          if (((ntb*128 + tcol) >> 9) == 0) v *= 0.125f;   // Q scale
        } else if constexpr (EPI == 2){
          v = fmaxf(v, 0.f);
        }
        ldsAll[trow*BSTR + tcol] = f2bf(v);
      }
    }
  }
  __syncthreads();

  const int rchunk = tid & 15;
  #pragma unroll
  for (int p=0;p<8;++p){
    const int trow = p*16 + (tid >> 4);
    const int grow = mt*128 + trow;
    const int gcol = ntb*128 + rchunk*8;
    u16x8 v = *reinterpret_cast<const u16x8*>(&ldsAll[trow*BSTR + rchunk*8]);
    if constexpr (EPI == 1){
      const float4* rp = reinterpret_cast<const float4*>(resf + (size_t)grow*N + gcol);
      float4 ra = rp[0], rb2 = rp[1];
      float rr[8] = {ra.x,ra.y,ra.z,ra.w,rb2.x,rb2.y,rb2.z,rb2.w};
      #pragma unroll
      for (int i=0;i<8;++i) v[i] = f2bf(bf2f(v[i]) + rr[i]);
    } else if constexpr (EPI == 5){
      u16x8 rv = *reinterpret_cast<const u16x8*>(resb + (size_t)grow*N + gcol);
      #pragma unroll
      for (int i=0;i<8;++i) v[i] = f2bf(bf2f(v[i]) + bf2f(rv[i]));
    }
    if constexpr (EPI == 0){
      const int bi = grow / NN, ni = grow - bi*NN;
      const int which = gcol >> 9, hh = (gcol >> 6) & 7, d = gcol & 63;
      *reinterpret_cast<u16x8*>(outb + (size_t)which*QKV_ELEMS +
          (((size_t)bi*HH + hh)*NN + ni)*DKk + d) = v;
    } else {
      *reinterpret_cast<u16x8*>(outb + (size_t)grow*N + gcol) = v;
    }
  }
}

// ---------------- fused segment attention (r13-verified, T5 setprio) ----------------
__global__ __launch_bounds__(256) void attn_kernel(
    const u16* __restrict__ Qg, const u16* __restrict__ Kg, const u16* __restrict__ Vg,
    const float* __restrict__ biasA, u16* __restrict__ ctx)
{
  __shared__ u16 Kb[NPAD*72];
  __shared__ u16 Vt[64*200];
  __shared__ u16 Pl[4*16*200];
  const int tid = threadIdx.x, lane = tid & 63, wave = tid >> 6;
  const int lo = lane & 15, hi = lane >> 4;
  const int bh = blockIdx.x;
  const int h = bh & 7, g = h >> 2, b = bh >> 3;
  const size_t base = (size_t)bh * NN * DKk;

  #pragma unroll
  for (int it=0; it<6; ++it){
    int row = it*32 + (tid >> 3);
    int cb = (tid & 7)*8;
    u16x8 val = {0,0,0,0,0,0,0,0};
    if (row < NN) val = *reinterpret_cast<const u16x8*>(Kg + base + (size_t)row*DKk + cb);
    *reinterpret_cast<u16x8*>(&Kb[row*72 + cb]) = val;
  }
  #pragma unroll
  for (int it=0; it<6; ++it){
    int row = it*32 + (tid >> 3);
    int cb = (tid & 7)*8;
    u16x8 val = {0,0,0,0,0,0,0,0};
    if (row < NN) val = *reinterpret_cast<const u16x8*>(Vg + base + (size_t)row*DKk + cb);
    *reinterpret_cast<u16x8*>(&Pl[row*64 + cb]) = val;
  }
  __syncthreads();
  #pragma unroll
  for (int j=0;j<6;++j){
    int task = j*256 + tid;
    int d = task & 63;
    int nc = task >> 6;
    u16x8 tv;
    #pragma unroll
    for (int i=0;i<8;++i) tv[i] = Pl[(nc*8+i)*64 + d];
    *reinterpret_cast<u16x8*>(&Vt[d*200 + nc*8]) = tv;
  }
  __syncthreads();

  u16* pw = Pl + wave*16*200;

  for (int rb = wave; rb < 12; rb += 4){
    const int q0 = rb*16;
    const int qrow = q0 + lo;
    bf16x8 qa[2];
    #pragma unroll
    for (int kk=0;kk<2;++kk){
      u16x8 val = {0,0,0,0,0,0,0,0};
      if (qrow < NN) val = *reinterpret_cast<const u16x8*>(Qg + base + (size_t)qrow*DKk + kk*32 + hi*8);
      qa[kk] = as_bf(val);
    }
    f32x4 s[12];
    __builtin_amdgcn_s_setprio(1);
    #pragma unroll
    for (int c=0;c<12;++c){
      f32x4 a = f32x4{0.f,0.f,0.f,0.f};
      #pragma unroll
      for (int kk=0;kk<2;++kk){
        bf16x8 kb = *reinterpret_cast<const bf16x8*>(&Kb[(c*16+lo)*72 + kk*32 + hi*8]);
        a = __builtin_amdgcn_mfma_f32_16x16x32_bf16(qa[kk], kb, a, 0,0,0);
      }
      s[c] = a;
    }
    __builtin_amdgcn_s_setprio(0);
    const float* brow = biasA + ((size_t)g*NPAD + q0 + hi*4)*NPAD + lo;
    #pragma unroll
    for (int r=0;r<4;++r)
      #pragma unroll
      for (int c=0;c<12;++c)
        s[c][r] += brow[r*NPAD + c*16];
    float inv[4];
    #pragma unroll
    for (int r=0;r<4;++r){
      float m = s[0][r];
      #pragma unroll
      for (int c=1;c<12;++c) m = fmaxf(m, s[c][r]);
      #pragma unroll
      for (int off=1; off<16; off<<=1) m = fmaxf(m, __shfl_xor(m, off, 64));
      float t = 0.f;
      #pragma unroll
      for (int c=0;c<12;++c){ float e = __expf(s[c][r] - m); s[c][r] = e; t += e; }
      #pragma unroll
      for (int off=1; off<16; off<<=1) t += __shfl_xor(t, off, 64);
      inv[r] = 1.0f / t;
    }
    #pragma unroll
    for (int c=0;c<12;++c)
      #pragma unroll
      for (int r=0;r<4;++r)
        pw[(hi*4+r)*200 + c*16 + lo] = f2bf(s[c][r] * inv[r]);
    asm volatile("s_waitcnt lgkmcnt(0)" ::: "memory");
    __builtin_amdgcn_sched_barrier(0);
    bf16x8 pa[6];
    #pragma unroll
    for (int c6=0;c6<6;++c6)
      pa[c6] = *reinterpret_cast<const bf16x8*>(&pw[lo*200 + c6*32 + hi*8]);
    __builtin_amdgcn_s_setprio(1);
    #pragma unroll
    for (int dt=0;dt<4;++dt){
      f32x4 a = f32x4{0.f,0.f,0.f,0.f};
      #pragma unroll
      for (int c6=0;c6<6;++c6){
        bf16x8 vb = *reinterpret_cast<const bf16x8*>(&Vt[(dt*16+lo)*200 + c6*32 + hi*8]);
        a = __builtin_amdgcn_mfma_f32_16x16x32_bf16(pa[c6], vb, a, 0,0,0);
      }
      #pragma unroll
      for (int r=0;r<4;++r){
        int q = q0 + hi*4 + r;
        if (q < NN)
          ctx[((size_t)b*NN + q)*DD + h*DKk + dt*16 + lo] = f2bf(a[r]);
      }
    }
    __builtin_amdgcn_s_setprio(0);
  }
}

// ---------------- LayerNorm over D=512, one wave per row ----------------
template<int OUTF32>
__global__ __launch_bounds__(256) void ln_kernel(
    const u16* __restrict__ in, const float* __restrict__ gamma,
    const float* __restrict__ beta, void* __restrict__ outp)
{
  const int row = blockIdx.x*4 + (threadIdx.x >> 6);
  const int lane = threadIdx.x & 63;
  u16x8 rv = *reinterpret_cast<const u16x8*>(in + (size_t)row*512 + lane*8);
  float x[8]; float s = 0.f, s2 = 0.f;
  #pragma unroll
  for (int i=0;i<8;++i){ x[i] = bf2f(rv[i]); s += x[i]; s2 += x[i]*x[i]; }
  #pragma unroll
  for (int off=32; off>=1; off>>=1){ s += __shfl_xor(s, off, 64); s2 += __shfl_xor(s2, off, 64); }
  const float mu = s * (1.f/512.f);
  const float var = s2 * (1.f/512.f) - mu*mu;
  const float rstd = rsqrtf(var + 1e-5f);
  float4 ga = *reinterpret_cast<const float4*>(gamma + lane*8);
  float4 gb = *reinterpret_cast<const float4*>(gamma + lane*8 + 4);
  float4 ba = *reinterpret_cast<const float4*>(beta + lane*8);
  float4 bb = *reinterpret_cast<const float4*>(beta + lane*8 + 4);
  float gg[8] = {ga.x,ga.y,ga.z,ga.w,gb.x,gb.y,gb.z,gb.w};
  float bt[8] = {ba.x,ba.y,ba.z,ba.w,bb.x,bb.y,bb.z,bb.w};
  if constexpr (OUTF32){
    float o[8];
    #pragma unroll
    for (int i=0;i<8;++i) o[i] = (x[i]-mu)*rstd*gg[i] + bt[i];
    float4* op = reinterpret_cast<float4*>((float*)outp + (size_t)row*512 + lane*8);
    op[0] = make_float4(o[0],o[1],o[2],o[3]);
    op[1] = make_float4(o[4],o[5],o[6],o[7]);
  } else {
    u16x8 o;
    #pragma unroll
    for (int i=0;i<8;++i) o[i] = f2bf((x[i]-mu)*rstd*gg[i] + bt[i]);
    *reinterpret_cast<u16x8*>((u16*)outp + (size_t)row*512 + lane*8) = o;
  }
}

// ---------------- launch ----------------
// ws map (total 196,384,768 B) — r2-r13 verified layout:
//   [0        ..  2097152) w1_b     [2097152 ..  4194304) w2_b
//   [4194304  ..  5767168) wqkv     [5767168 ..  6291456) wo_b
//   [6291456  ..  6586368) biasA    [6586368 ..  6592512) bqkv
//   [6592512  .. 54040576) xb : x bf16 -> ctx (x f32 residual read from d_in)
//   [54040576 ..101488640) qbuf: Q -> r1
//   [101488640..148936704) kbuf: K -> h
//   [148936704..196384768) vbuf: V -> s2
//   ffbuf = ws+4194304: FF1 chunk 23296x2048x2B = 95,420,416 ends 99,614,720 < kbuf
extern "C" void kernel_launch(void* const* d_in, const int* in_sizes, int n_in,
                              void* d_out, int out_size, void* d_ws, size_t ws_size,
                              hipStream_t stream)
{
  if (ws_size < WS_NEEDED) return;

  const float* x   = (const float*)d_in[0];
  const int*   mask= (const int*)  d_in[1];
  const float* Wq  = (const float*)d_in[2];
  const float* bq  = (const float*)d_in[3];
  const float* Wk  = (const float*)d_in[4];
  const float* bk  = (const float*)d_in[5];
  const float* Wv  = (const float*)d_in[6];
  const float* bv  = (const float*)d_in[7];
  const float* Wo  = (const float*)d_in[8];
  const float* bo  = (const float*)d_in[9];
  const float* w1  = (const float*)d_in[10];
  const float* b1  = (const float*)d_in[11];
  const float* w2  = (const float*)d_in[12];
  const float* b2  = (const float*)d_in[13];
  const float* g1  = (const float*)d_in[14];
  const float* be1 = (const float*)d_in[15];
  const float* g2  = (const float*)d_in[16];
  const float* be2 = (const float*)d_in[17];

  char* ws = (char*)d_ws;
  u16*   w1_b  = (u16*)  (ws + 0);
  u16*   w2_b  = (u16*)  (ws + 2097152);
  u16*   wqkv  = (u16*)  (ws + 4194304);
  u16*   wo_b  = (u16*)  (ws + 5767168);
  float* biasA = (float*)(ws + 6291456);
  float* bqkv  = (float*)(ws + 6586368);
  u16*   xb    = (u16*)  (ws + 6592512);
  u16*   qbuf  = (u16*)  (ws + 54040576);
  u16*   kbuf  = qbuf + QKV_ELEMS;
  u16*   vbuf  = qbuf + 2*QKV_ELEMS;
  u16*   ffbuf = (u16*)  (ws + 4194304);

  // one fused prep launch
  prep_kernel<<<13157, 256, 0, stream>>>(x, Wq, Wk, Wv, Wo, w1, w2, bq, bk, bv,
                                         mask, xb, wqkv, wo_b, w1_b, w2_b, biasA, bqkv);

  // QKV projection — fastest measured variant (r10 gemmT 4-wave, 98 µs)
  gemmT<0><<<dim3(12,362), 256, 0, stream>>>(xb, wqkv, 512, 1536, 512, 512,
                                             bqkv, qbuf, nullptr, nullptr);
  // fused segment attention -> ctx (overwrites xb; x f32 stays in d_in)
  attn_kernel<<<2048, 256, 0, stream>>>(qbuf, kbuf, vbuf, biasA, xb);
  // Wo projection + bo + x (f32) residual -> r1 (qbuf)
  gemmT<1><<<dim3(4,362), 256, 0, stream>>>(xb, wo_b, 512, 512, 512, 512,
                                            bo, qbuf, x, nullptr);
  // LN1 -> h (kbuf)
  ln_kernel<0><<<11584, 256, 0, stream>>>(qbuf, g1, be1, kbuf);
  // FFN split-M: chunks of 91 + 90 tiles of 256 rows (FF1 = gemm8, r12-best)
  {
    const size_t ro = (size_t)23296 * 512;
    gemm8<2><<<dim3(8,91), 512, 0, stream>>>(kbuf, w1_b, 512, 2048, 512, 512,
                                             b1, ffbuf);
    gemmT<5><<<dim3(4,182), 256, 0, stream>>>(ffbuf, w2_b, 2048, 512, 2048, 2048,
                                              b2, vbuf, nullptr, kbuf);
    gemm8<2><<<dim3(8,90), 512, 0, stream>>>(kbuf + ro, w1_b, 512, 2048, 512, 512,
                                             b1, ffbuf);
    gemmT<5><<<dim3(4,180), 256, 0, stream>>>(ffbuf, w2_b, 2048, 512, 2048, 2048,
                                              b2, vbuf + ro, nullptr, kbuf + ro);
  }
  // LN2 -> d_out (fp32)
  ln_kernel<1><<<11584, 256, 0, stream>>>(vbuf, g2, be2, d_out);
}